// Round 16
// baseline (65.380 us; speedup 1.0000x reference)
//
#include <hip/hip_runtime.h>
#include <stdint.h>

#define NVOX 128
#define VOL  (NVOX * NVOX * NVOX)
#define SLICE (NVOX * NVOX)
#define WPS  (SLICE / 2)              // u32 words per packed slice
#define PVOL (VOL / 2)                // u32 words per packed volume
#define NTHREADS 512
#define NREP 8                        // replica volumes: z=3, y=3, x=2
#define LO   (-200.0f)
#define VPIX 3.125f                   // 400/128
#define INV_V 0.32f                   // 1/3.125

// c = pi/18. NEGV2L = -c*V^2*log2(e). Weights as fn of frac g = fy-floor(fy):
// wy0 = 2^(NEGV2L*(g+1)^2); u = 2^(-NEGV2L*(2g+1)); wy1 = wy0*u; wy2 = wy1*u*C2
#define NEGV2L (-2.4589628f)
#define NU_G   (4.9179256f)           // -2*NEGV2L
#define NU_C   (2.4589628f)           // -NEGV2L
#define C2     (0.0330793f)           // 2^(2*NEGV2L)
#define FSCALE 1024.0f                // u16 fixed-point scale (2^10)
#define INV_FSCALE (1.0f / 1024.0f)
#define MAGIC  12582912.0f            // 1.5*2^23: fma(w,s,MAGIC) -> rn int low bits

// quad tile: 132x132 u16 cells viewed as 66x66 2x2-cell u64 quads.
// quad u64 fields: [c0r0(15:0), c1r0(31:16), c0r1(47:32), c1r1(63:48)]
#define QW 66
#define QSZ (QW * QW)                 // 4356 u64 = 34,848 B -> 4 blocks/CU

struct DepT {
    float wy0, wy1, wy2, wz0, wz1, wz2;
    int qb, sh, ry;
};

__device__ __forceinline__ DepT dep_compute(float4 v, float prF, float t) {
    DepT d;
    float fy = fmaf(t, v.y, v.x);          // voxel-frac coords (prep pre-folded)
    float fz = fmaf(t, v.w, v.z);
    float ffy = floorf(fy), ffz = floorf(fz);
    float gy = fy - ffy, hy = gy + 1.0f;
    d.wy0 = exp2f(NEGV2L * hy * hy) * prF;
    float uy = exp2f(fmaf(NU_G, gy, NU_C));
    d.wy1 = d.wy0 * uy;
    d.wy2 = d.wy1 * (uy * C2);
    float gz = fz - ffz, hz = gz + 1.0f;
    d.wz0 = exp2f(NEGV2L * hz * hz);
    float uz = exp2f(fmaf(NU_G, gz, NU_C));
    d.wz1 = d.wz0 * uz;
    d.wz2 = d.wz1 * (uz * C2);
    int row = (int)ffy + 1;                // iy0 + 2, in [0,128]
    int col = (int)ffz + 1;                // iz0 + 2, in [0,129]
    d.sh = (col & 1) << 4;
    d.ry = row & 1;
    d.qb = (row >> 1) * QW + (col >> 1);   // top-left quad of the 2x2 span
    return d;
}

// 4 ds_add_u64 per visit (was 6 ds_add_u32): the 3x3 footprint spans exactly
// 2x2 aligned quads. Row-parity selection is 8 cndmasks; all 4 atomics share
// one base with immediate ds offsets.
__device__ __forceinline__ void dep_fire(const DepT& d, unsigned long long* qt) {
    float wyc[3] = { d.wy0, d.wy1, d.wy2 };
    unsigned l[3], h[3];
    #pragma unroll
    for (int oy = 0; oy < 3; ++oy) {
        float w = wyc[oy];
        unsigned f0 = __float_as_uint(fmaf(w, d.wz0, MAGIC));
        unsigned f1 = __float_as_uint(fmaf(w, d.wz1, MAGIC));
        unsigned f2 = __float_as_uint(fmaf(w, d.wz2, MAGIC));
        unsigned lo = __builtin_amdgcn_perm(f1, f0, 0x05040100u); // f0.lo16|f1.lo16<<16
        unsigned hi = f2 & 0xFFFFu;
        unsigned long long V = ((unsigned long long)hi << 32) | lo;
        V <<= d.sh;
        l[oy] = (unsigned)V;
        h[oy] = (unsigned)(V >> 32);
    }
    bool o = (d.ry != 0);
    // 4x4 row window: o==0 -> rows {V0,V1,V2,0}; o==1 -> {0,V0,V1,V2}
    unsigned tA = o ? 0u   : l[0], tB = o ? l[0] : l[1];
    unsigned tC = o ? 0u   : h[0], tD = o ? h[0] : h[1];
    unsigned bA = o ? l[1] : l[2], bB = o ? l[2] : 0u;
    unsigned bC = o ? h[1] : h[2], bD = o ? h[2] : 0u;
    atomicAdd(&qt[d.qb],          tA | ((unsigned long long)tB << 32));
    atomicAdd(&qt[d.qb + 1],      tC | ((unsigned long long)tD << 32));
    atomicAdd(&qt[d.qb + QW],     bA | ((unsigned long long)bB << 32));
    atomicAdd(&qt[d.qb + QW + 1], bC | ((unsigned long long)bD << 32));
}

// Fused back-projection over all 3 directions. blockIdx.y in [0,8):
// 0-2 = z chunks, 3-5 = y chunks, 6-7 = x chunks -> 1024 blocks = 4/CU.
// u16 quad-packed LDS tile, integer ds_add_u64 (4/visit); explicit ILP-2
// paired deposits (round 15).
__global__ __launch_bounds__(NTHREADS, 8) void bp_fused(
    const float4* __restrict__ pk,    // [dir][nlor] = (Ay, By, Az, Bz)
    const float*  __restrict__ projF, // [dir][nlor] = proj * FSCALE
    unsigned* __restrict__ vols,      // NREP packed volumes
    int nlor)
{
    __shared__ unsigned long long qtile[QSZ];
    const int k  = blockIdx.x;
    const int gy = blockIdx.y;
    const int dir   = (gy < 3) ? 0 : (gy < 6) ? 1 : 2;
    const int chunk = gy - dir * 3;
    const int nsd   = (dir == 2) ? 2 : 3;

    const float4* p   = pk + (size_t)dir * nlor;
    const float*  prf = projF + (size_t)dir * nlor;
    unsigned* vol = vols + (size_t)gy * PVOL;
    const int n0 = (int)(((long long)chunk * nlor) / nsd);
    const int n1 = (int)(((long long)(chunk + 1) * nlor) / nsd);

    for (int i = threadIdx.x; i < QSZ; i += NTHREADS) qtile[i] = 0ull;
    __syncthreads();

    const float t = (k + 0.5f) * 0.0078125f;   // (k+0.5)/128; sweep endpoints ±200

    int n = n0 + (int)threadIdx.x;
    for (; n + NTHREADS < n1; n += 2 * NTHREADS) {
        float4 vA = p[n];              float pA = prf[n];
        float4 vB = p[n + NTHREADS];   float pB = prf[n + NTHREADS];
        DepT dA = dep_compute(vA, pA, t);
        DepT dB = dep_compute(vB, pB, t);
        dep_fire(dA, qtile);
        dep_fire(dB, qtile);
    }
    if (n < n1) {
        DepT dA = dep_compute(p[n], prf[n], t);
        dep_fire(dA, qtile);
    }
    __syncthreads();

    // flush inner 128x128 as u16-packed u32 words (same vol format as before):
    // output word i = (iy, w) covers cols 2w+2,2w+3 of row iy+2 -> quad
    // (row>>1, w+1), row-parity selects lo/hi half.
    unsigned* dst = vol + (size_t)k * WPS;
    for (int i = threadIdx.x; i < WPS; i += NTHREADS) {
        int iy = i >> 6, w = i & 63;
        int row = iy + 2;
        unsigned long long q = qtile[(row >> 1) * QW + (w + 1)];
        dst[i] = (row & 1) ? (unsigned)(q >> 32) : (unsigned)q;
    }
}

// prep: pk[dir][n] = (Ay, By, Az, Bz) with A = c1*INV_V + 63.5, B = (c2-c1)*INV_V
// projF[dir][n] = proj * FSCALE
__global__ __launch_bounds__(256) void prep(
    const float* __restrict__ lz, const float* __restrict__ ly,
    const float* __restrict__ lx,
    const float* __restrict__ pz, const float* __restrict__ py,
    const float* __restrict__ px,
    float4* __restrict__ pk, float* __restrict__ projF, int nlor)
{
    int n = blockIdx.x * 256 + threadIdx.x;
    if (n >= nlor) return;
    const float* l  = (blockIdx.y == 0) ? lz : (blockIdx.y == 1) ? ly : lx;
    const float* pr = (blockIdx.y == 0) ? pz : (blockIdx.y == 1) ? py : px;
    float y1 = l[1 * nlor + n], z1 = l[2 * nlor + n];
    float y2 = l[4 * nlor + n], z2 = l[5 * nlor + n];
    pk[(size_t)blockIdx.y * nlor + n] =
        make_float4(fmaf(y1, INV_V, 63.5f), (y2 - y1) * INV_V,
                    fmaf(z1, INV_V, 63.5f), (z2 - z1) * INV_V);
    projF[(size_t)blockIdx.y * nlor + n] = pr[n] * FSCALE;
}

// Fused merge on packed vols: z = reps 0-2, y = reps 3-5, x = reps 6-7.
// out[a][b][c] = Σ vz[a][b][c] + Σ vy[b][a][c] + Σ vx[c][a][b]
__global__ __launch_bounds__(256) void merge_all(
    float2* __restrict__ out, const unsigned* __restrict__ vols)
{
    __shared__ float T[64][65];
    const unsigned* vz = vols;
    const unsigned* vy = vols + 3 * (size_t)PVOL;
    const unsigned* vx = vols + 6 * (size_t)PVOL;
    int a  = blockIdx.x;
    int tb = (blockIdx.y & 1) * 64;
    int tc = (blockIdx.y >> 1) * 64;
    int wb = threadIdx.x & 31;       // word column
    int r0 = threadIdx.x >> 5;       // 0..7

    for (int cc = r0; cc < 64; cc += 8) {
        size_t wi = ((size_t)(tc + cc) * NVOX + a) * 64 + (tb >> 1) + wb;
        unsigned lo = 0, hi = 0;
        #pragma unroll
        for (int r = 0; r < 2; ++r) {
            unsigned w = vx[(size_t)r * PVOL + wi];
            lo += w & 0xFFFFu; hi += w >> 16;
        }
        T[cc][2 * wb]     = (float)lo * INV_FSCALE;
        T[cc][2 * wb + 1] = (float)hi * INV_FSCALE;
    }
    __syncthreads();
    for (int bb = r0; bb < 64; bb += 8) {
        int b = tb + bb;
        size_t zi = ((size_t)a * NVOX + b) * 64 + (tc >> 1) + wb;
        size_t yi = ((size_t)b * NVOX + a) * 64 + (tc >> 1) + wb;
        unsigned lo = 0, hi = 0;
        #pragma unroll
        for (int r = 0; r < 3; ++r) {
            unsigned wz = vz[(size_t)r * PVOL + zi];
            unsigned wy = vy[(size_t)r * PVOL + yi];
            lo += (wz & 0xFFFFu) + (wy & 0xFFFFu);
            hi += (wz >> 16) + (wy >> 16);
        }
        out[zi] = make_float2((float)lo * INV_FSCALE + T[2 * wb][bb],
                              (float)hi * INV_FSCALE + T[2 * wb + 1][bb]);
    }
}

// Ultra-fallback: direct device-scope scatter (round-1 proven).
template<int DIR>
__global__ __launch_bounds__(256) void bp_direct(
    const float* __restrict__ lors, const float* __restrict__ proj,
    float* __restrict__ out, int nlor)
{
    int tid = blockIdx.x * 256 + threadIdx.x;
    int k = tid & (NVOX - 1);
    int n = tid >> 7;
    if (n >= nlor) return;

    float p1x = lors[0 * nlor + n];
    float p1y = lors[1 * nlor + n];
    float p1z = lors[2 * nlor + n];
    float p2x = lors[3 * nlor + n];
    float p2y = lors[4 * nlor + n];
    float p2z = lors[5 * nlor + n];
    float pr  = proj[n];

    float xk = LO + (k + 0.5f) * VPIX;
    float t  = (xk - p1x) / (p2x - p1x);
    if (t < 0.0f || t > 1.0f) return;

    float y = p1y + t * (p2y - p1y);
    float z = p1z + t * (p2z - p1z);
    float fy = (y - LO) * INV_V - 0.5f;
    float fz = (z - LO) * INV_V - 0.5f;
    int iy0 = (int)floorf(fy) - 1;
    int iz0 = (int)floorf(fz) - 1;

    const float NEG = -0.17453292519943295f;   // -pi/18
    float wy[3], wz[3];
    #pragma unroll
    for (int o = 0; o < 3; ++o) {
        int iy = iy0 + o;
        float dy = (iy + 0.5f) * VPIX + LO - y;
        wy[o] = (iy >= 0 && iy < NVOX) ? __expf(NEG * dy * dy) * pr : 0.0f;
        int iz = iz0 + o;
        float dz = (iz + 0.5f) * VPIX + LO - z;
        wz[o] = (iz >= 0 && iz < NVOX) ? __expf(NEG * dz * dz) : 0.0f;
    }
    #pragma unroll
    for (int oy = 0; oy < 3; ++oy) {
        if (wy[oy] == 0.0f) continue;
        int iy = iy0 + oy;
        #pragma unroll
        for (int oz = 0; oz < 3; ++oz) {
            if (wz[oz] == 0.0f) continue;
            int iz = iz0 + oz;
            int idx = (DIR == 0) ? (iy * NVOX + iz) * NVOX + k
                    : (DIR == 1) ? (iy * NVOX + k) * NVOX + iz
                                 : (k * NVOX + iy) * NVOX + iz;
            atomicAdd(&out[idx], wy[oy] * wz[oz]);
        }
    }
}

extern "C" void kernel_launch(void* const* d_in, const int* in_sizes, int n_in,
                              void* d_out, int out_size, void* d_ws, size_t ws_size,
                              hipStream_t stream) {
    const float* xlors = (const float*)d_in[4];
    const float* ylors = (const float*)d_in[5];
    const float* zlors = (const float*)d_in[6];
    const float* xproj = (const float*)d_in[7];
    const float* yproj = (const float*)d_in[8];
    const float* zproj = (const float*)d_in[9];
    float* out = (float*)d_out;
    const int nlor = in_sizes[7];
    const size_t volsB = (size_t)NREP * PVOL * sizeof(unsigned);  // 33.6 MB
    const size_t pkB   = 3 * (size_t)nlor * sizeof(float4);
    const size_t pfB   = 3 * (size_t)nlor * sizeof(float);

    if (ws_size >= volsB + pkB + pfB && (nlor & 1) == 0) {
        unsigned* vols = (unsigned*)d_ws;
        float4* pkv   = (float4*)((char*)d_ws + volsB);
        float*  projF = (float*)((char*)d_ws + volsB + pkB);

        dim3 pgrid((nlor + 255) / 256, 3);
        prep<<<pgrid, 256, 0, stream>>>(zlors, ylors, xlors,
                                        zproj, yproj, xproj, pkv, projF, nlor);

        dim3 bgrid(NVOX, NREP);               // 1024 blocks = exactly 4/CU
        bp_fused<<<bgrid, NTHREADS, 0, stream>>>(pkv, projF, vols, nlor);

        dim3 mgrid(NVOX, 4);
        merge_all<<<mgrid, 256, 0, stream>>>((float2*)out, vols);
    } else {
        hipMemsetAsync(d_out, 0, (size_t)VOL * sizeof(float), stream);
        const int blocks = (nlor * NVOX + 255) / 256;
        bp_direct<0><<<blocks, 256, 0, stream>>>(xlors, xproj, out, nlor);
        bp_direct<1><<<blocks, 256, 0, stream>>>(ylors, yproj, out, nlor);
        bp_direct<2><<<blocks, 256, 0, stream>>>(zlors, zproj, out, nlor);
    }
}

// Round 17
// 60.325 us; speedup vs baseline: 1.0838x; 1.0838x over previous
//
#include <hip/hip_runtime.h>
#include <stdint.h>

#define NVOX 128
#define VOL  (NVOX * NVOX * NVOX)
#define SLICE (NVOX * NVOX)
#define WPS  (SLICE / 2)              // u32 words per packed slice
#define PVOL (VOL / 2)                // u32 words per packed volume
#define NTHREADS 512
#define NREP 8                        // replica volumes: z=3, y=3, x=2
#define LO   (-200.0f)
#define VPIX 3.125f                   // 400/128
#define INV_V 0.32f                   // 1/3.125

// c = pi/18. NEGV2L = -c*V^2*log2(e). Weights as fn of frac g = fy-floor(fy):
// wy0 = 2^(NEGV2L*(g+1)^2); u = 2^(-NEGV2L*(2g+1)); wy1 = wy0*u; wy2 = wy1*u*C2
#define NEGV2L (-2.4589628f)
#define NU_G   (4.9179256f)           // -2*NEGV2L
#define NU_C   (2.4589628f)           // -NEGV2L
#define C2     (0.0330793f)           // 2^(2*NEGV2L)
#define FSCALE 1024.0f                // u16 fixed-point scale (2^10)
#define INV_FSCALE (1.0f / 1024.0f)
#define MAGIC  12582912.0f            // 1.5*2^23: fma(w,s,MAGIC) -> rn int low bits

// padded tile: rows iy in [-2,129], cols iz in [-2,129] packed 2 cells/word
#define TROWS 132
#define TWORDS 66
#define TSZ (TROWS * TWORDS)          // 8712 u32 = 34.8 KB -> 4 blocks/CU

// ROUND 16 LESSON (reverted): 4x ds_add_u64 quads REGRESSED vs 6x ds_add_u32
// (54.0 vs 48.3 µs) — LDS atomics are bank-access-bound (u64 = 2 banks/lane:
// 8 accesses/visit > 6). The 6x u32 scheme is bank-minimal for a 3x3 footprint.

struct DepT {
    float wy0, wy1, wy2, wz0, wz1, wz2;
    int w0, sh;
};

__device__ __forceinline__ DepT dep_compute(float4 v, float prF, float t) {
    DepT d;
    float fy = fmaf(t, v.y, v.x);          // voxel-frac coords (prep pre-folded)
    float fz = fmaf(t, v.w, v.z);
    float ffy = floorf(fy), ffz = floorf(fz);
    float gy = fy - ffy, hy = gy + 1.0f;
    d.wy0 = exp2f(NEGV2L * hy * hy) * prF;
    float uy = exp2f(fmaf(NU_G, gy, NU_C));
    d.wy1 = d.wy0 * uy;
    d.wy2 = d.wy1 * (uy * C2);
    float gz = fz - ffz, hz = gz + 1.0f;
    d.wz0 = exp2f(NEGV2L * hz * hz);
    float uz = exp2f(fmaf(NU_G, gz, NU_C));
    d.wz1 = d.wz0 * uz;
    d.wz2 = d.wz1 * (uz * C2);
    int row = (int)ffy + 1;                // iy0 + 2
    int col = (int)ffz + 1;                // iz0 + 2
    d.sh = (col & 1) << 4;
    d.w0 = row * TWORDS + (col >> 1);
    return d;
}

__device__ __forceinline__ void dep_fire(const DepT& d, unsigned* tile) {
    float wyc[3] = { d.wy0, d.wy1, d.wy2 };
    #pragma unroll
    for (int oy = 0; oy < 3; ++oy) {
        float w = wyc[oy];
        unsigned f0 = __float_as_uint(fmaf(w, d.wz0, MAGIC));
        unsigned f1 = __float_as_uint(fmaf(w, d.wz1, MAGIC));
        unsigned f2 = __float_as_uint(fmaf(w, d.wz2, MAGIC));
        unsigned lo = __builtin_amdgcn_perm(f1, f0, 0x05040100u); // f0.lo16|f1.lo16<<16
        unsigned hi = f2 & 0xFFFFu;
        unsigned long long V = ((unsigned long long)hi << 32) | lo;
        V <<= d.sh;
        int b = d.w0 + oy * TWORDS;
        atomicAdd(&tile[b],     (unsigned)V);
        atomicAdd(&tile[b + 1], (unsigned)(V >> 32));
    }
}

// Fused back-projection over all 3 directions. blockIdx.y in [0,8):
// 0-2 = z chunks, 3-5 = y chunks, 6-7 = x chunks -> 1024 blocks = 4/CU.
// u16-pair packed LDS tile, integer ds_add (bank-parallel — round 8's 7.5x
// win). Explicit 2-way paired deposits (forced ILP-2, round 15).
__global__ __launch_bounds__(NTHREADS, 8) void bp_fused(
    const float4* __restrict__ pk,    // [dir][nlor] = (Ay, By, Az, Bz)
    const float*  __restrict__ projF, // [dir][nlor] = proj * FSCALE
    unsigned* __restrict__ vols,      // NREP packed volumes
    int nlor)
{
    __shared__ unsigned tile[TSZ];
    const int k  = blockIdx.x;
    const int gy = blockIdx.y;
    const int dir   = (gy < 3) ? 0 : (gy < 6) ? 1 : 2;
    const int chunk = gy - dir * 3;
    const int nsd   = (dir == 2) ? 2 : 3;

    const float4* p   = pk + (size_t)dir * nlor;
    const float*  prf = projF + (size_t)dir * nlor;
    unsigned* vol = vols + (size_t)gy * PVOL;
    const int n0 = (int)(((long long)chunk * nlor) / nsd);
    const int n1 = (int)(((long long)(chunk + 1) * nlor) / nsd);

    for (int i = threadIdx.x; i < TSZ; i += NTHREADS) tile[i] = 0u;
    __syncthreads();

    const float t = (k + 0.5f) * 0.0078125f;   // (k+0.5)/128; sweep endpoints ±200

    int n = n0 + (int)threadIdx.x;
    for (; n + NTHREADS < n1; n += 2 * NTHREADS) {
        float4 vA = p[n];              float pA = prf[n];
        float4 vB = p[n + NTHREADS];   float pB = prf[n + NTHREADS];
        DepT dA = dep_compute(vA, pA, t);
        DepT dB = dep_compute(vB, pB, t);
        dep_fire(dA, tile);
        dep_fire(dB, tile);
    }
    if (n < n1) {
        DepT dA = dep_compute(p[n], prf[n], t);
        dep_fire(dA, tile);
    }
    __syncthreads();

    // flush inner 64 words/row (cols 2..129 = iz 0..127), still u16-packed
    unsigned* dst = vol + (size_t)k * WPS;
    for (int i = threadIdx.x; i < WPS; i += NTHREADS) {
        int iy = i >> 6, w = i & 63;
        dst[i] = tile[(iy + 2) * TWORDS + w + 1];
    }
}

// prep: pk[dir][n] = (Ay, By, Az, Bz) with A = c1*INV_V + 63.5, B = (c2-c1)*INV_V
// projF[dir][n] = proj * FSCALE
__global__ __launch_bounds__(256) void prep(
    const float* __restrict__ lz, const float* __restrict__ ly,
    const float* __restrict__ lx,
    const float* __restrict__ pz, const float* __restrict__ py,
    const float* __restrict__ px,
    float4* __restrict__ pk, float* __restrict__ projF, int nlor)
{
    int n = blockIdx.x * 256 + threadIdx.x;
    if (n >= nlor) return;
    const float* l  = (blockIdx.y == 0) ? lz : (blockIdx.y == 1) ? ly : lx;
    const float* pr = (blockIdx.y == 0) ? pz : (blockIdx.y == 1) ? py : px;
    float y1 = l[1 * nlor + n], z1 = l[2 * nlor + n];
    float y2 = l[4 * nlor + n], z2 = l[5 * nlor + n];
    pk[(size_t)blockIdx.y * nlor + n] =
        make_float4(fmaf(y1, INV_V, 63.5f), (y2 - y1) * INV_V,
                    fmaf(z1, INV_V, 63.5f), (z2 - z1) * INV_V);
    projF[(size_t)blockIdx.y * nlor + n] = pr[n] * FSCALE;
}

// Fused merge on packed vols: z = reps 0-2, y = reps 3-5, x = reps 6-7.
// out[a][b][c] = Σ vz[a][b][c] + Σ vy[b][a][c] + Σ vx[c][a][b]
__global__ __launch_bounds__(256) void merge_all(
    float2* __restrict__ out, const unsigned* __restrict__ vols)
{
    __shared__ float T[64][65];
    const unsigned* vz = vols;
    const unsigned* vy = vols + 3 * (size_t)PVOL;
    const unsigned* vx = vols + 6 * (size_t)PVOL;
    int a  = blockIdx.x;
    int tb = (blockIdx.y & 1) * 64;
    int tc = (blockIdx.y >> 1) * 64;
    int wb = threadIdx.x & 31;       // word column
    int r0 = threadIdx.x >> 5;       // 0..7

    for (int cc = r0; cc < 64; cc += 8) {
        size_t wi = ((size_t)(tc + cc) * NVOX + a) * 64 + (tb >> 1) + wb;
        unsigned lo = 0, hi = 0;
        #pragma unroll
        for (int r = 0; r < 2; ++r) {
            unsigned w = vx[(size_t)r * PVOL + wi];
            lo += w & 0xFFFFu; hi += w >> 16;
        }
        T[cc][2 * wb]     = (float)lo * INV_FSCALE;
        T[cc][2 * wb + 1] = (float)hi * INV_FSCALE;
    }
    __syncthreads();
    for (int bb = r0; bb < 64; bb += 8) {
        int b = tb + bb;
        size_t zi = ((size_t)a * NVOX + b) * 64 + (tc >> 1) + wb;
        size_t yi = ((size_t)b * NVOX + a) * 64 + (tc >> 1) + wb;
        unsigned lo = 0, hi = 0;
        #pragma unroll
        for (int r = 0; r < 3; ++r) {
            unsigned wz = vz[(size_t)r * PVOL + zi];
            unsigned wy = vy[(size_t)r * PVOL + yi];
            lo += (wz & 0xFFFFu) + (wy & 0xFFFFu);
            hi += (wz >> 16) + (wy >> 16);
        }
        out[zi] = make_float2((float)lo * INV_FSCALE + T[2 * wb][bb],
                              (float)hi * INV_FSCALE + T[2 * wb + 1][bb]);
    }
}

// Ultra-fallback: direct device-scope scatter (round-1 proven).
template<int DIR>
__global__ __launch_bounds__(256) void bp_direct(
    const float* __restrict__ lors, const float* __restrict__ proj,
    float* __restrict__ out, int nlor)
{
    int tid = blockIdx.x * 256 + threadIdx.x;
    int k = tid & (NVOX - 1);
    int n = tid >> 7;
    if (n >= nlor) return;

    float p1x = lors[0 * nlor + n];
    float p1y = lors[1 * nlor + n];
    float p1z = lors[2 * nlor + n];
    float p2x = lors[3 * nlor + n];
    float p2y = lors[4 * nlor + n];
    float p2z = lors[5 * nlor + n];
    float pr  = proj[n];

    float xk = LO + (k + 0.5f) * VPIX;
    float t  = (xk - p1x) / (p2x - p1x);
    if (t < 0.0f || t > 1.0f) return;

    float y = p1y + t * (p2y - p1y);
    float z = p1z + t * (p2z - p1z);
    float fy = (y - LO) * INV_V - 0.5f;
    float fz = (z - LO) * INV_V - 0.5f;
    int iy0 = (int)floorf(fy) - 1;
    int iz0 = (int)floorf(fz) - 1;

    const float NEG = -0.17453292519943295f;   // -pi/18
    float wy[3], wz[3];
    #pragma unroll
    for (int o = 0; o < 3; ++o) {
        int iy = iy0 + o;
        float dy = (iy + 0.5f) * VPIX + LO - y;
        wy[o] = (iy >= 0 && iy < NVOX) ? __expf(NEG * dy * dy) * pr : 0.0f;
        int iz = iz0 + o;
        float dz = (iz + 0.5f) * VPIX + LO - z;
        wz[o] = (iz >= 0 && iz < NVOX) ? __expf(NEG * dz * dz) : 0.0f;
    }
    #pragma unroll
    for (int oy = 0; oy < 3; ++oy) {
        if (wy[oy] == 0.0f) continue;
        int iy = iy0 + oy;
        #pragma unroll
        for (int oz = 0; oz < 3; ++oz) {
            if (wz[oz] == 0.0f) continue;
            int iz = iz0 + oz;
            int idx = (DIR == 0) ? (iy * NVOX + iz) * NVOX + k
                    : (DIR == 1) ? (iy * NVOX + k) * NVOX + iz
                                 : (k * NVOX + iy) * NVOX + iz;
            atomicAdd(&out[idx], wy[oy] * wz[oz]);
        }
    }
}

extern "C" void kernel_launch(void* const* d_in, const int* in_sizes, int n_in,
                              void* d_out, int out_size, void* d_ws, size_t ws_size,
                              hipStream_t stream) {
    const float* xlors = (const float*)d_in[4];
    const float* ylors = (const float*)d_in[5];
    const float* zlors = (const float*)d_in[6];
    const float* xproj = (const float*)d_in[7];
    const float* yproj = (const float*)d_in[8];
    const float* zproj = (const float*)d_in[9];
    float* out = (float*)d_out;
    const int nlor = in_sizes[7];
    const size_t volsB = (size_t)NREP * PVOL * sizeof(unsigned);  // 33.6 MB
    const size_t pkB   = 3 * (size_t)nlor * sizeof(float4);
    const size_t pfB   = 3 * (size_t)nlor * sizeof(float);

    if (ws_size >= volsB + pkB + pfB && (nlor & 1) == 0) {
        unsigned* vols = (unsigned*)d_ws;
        float4* pkv   = (float4*)((char*)d_ws + volsB);
        float*  projF = (float*)((char*)d_ws + volsB + pkB);

        dim3 pgrid((nlor + 255) / 256, 3);
        prep<<<pgrid, 256, 0, stream>>>(zlors, ylors, xlors,
                                        zproj, yproj, xproj, pkv, projF, nlor);

        dim3 bgrid(NVOX, NREP);               // 1024 blocks = exactly 4/CU
        bp_fused<<<bgrid, NTHREADS, 0, stream>>>(pkv, projF, vols, nlor);

        dim3 mgrid(NVOX, 4);
        merge_all<<<mgrid, 256, 0, stream>>>((float2*)out, vols);
    } else {
        hipMemsetAsync(d_out, 0, (size_t)VOL * sizeof(float), stream);
        const int blocks = (nlor * NVOX + 255) / 256;
        bp_direct<0><<<blocks, 256, 0, stream>>>(xlors, xproj, out, nlor);
        bp_direct<1><<<blocks, 256, 0, stream>>>(ylors, yproj, out, nlor);
        bp_direct<2><<<blocks, 256, 0, stream>>>(zlors, zproj, out, nlor);
    }
}